// Round 4
// baseline (950.443 us; speedup 1.0000x reference)
//
#include <hip/hip_runtime.h>

// ConvLSTM2D (B=16,T=5,H=W=256,Cin=3,F=8) + BN + LeakyReLU + Dense(8->2)
// Round-13: persistent kernel (r12 base, passed @432us) with CONCURRENCY FIX.
// r12 counters: hbm 405 GB/s (5%), MfmaUtil 6.8%, occupancy 24% -> memory
// latency not hidden (2 blocks/CU, lockstep waves, serialized slots).
// Now: NBLK=1024 / SLOTS=2 / launch_bounds(256,4) -> 4 blocks/CU (16 waves),
// LDS 31KB/block (cls halves to 16KB); slot-1 global loads issued before
// slot-0 compute so slot-1 HBM latency hides under MFMA+gate work.
// c stays in LDS whole run (traffic stays ~176MB, r12-verified).

#define BB  16
#define TT  5
#define HH  256
#define WW  256
#define CIN 3
#define FF  8
#define GG  32

#define TW  32   // tile width (pixels)
#define THT 16   // tile height
#define LW  34   // TW+2 halo
#define LH  18   // THT+2 halo
#define NG  8    // 16x16-px groups per wave

#define NBLK  1024  // persistent blocks (4 per CU)
#define SLOTS 2     // tiles per block = 2048/NBLK

#define LOG2E 1.44269504088896340736f

typedef _Float16 half8  __attribute__((ext_vector_type(8)));
typedef _Float16 half4  __attribute__((ext_vector_type(4)));
typedef _Float16 half2t __attribute__((ext_vector_type(2)));
typedef float    floatx4 __attribute__((ext_vector_type(4)));

__device__ __forceinline__ float frcp(float x) { return __builtin_amdgcn_rcpf(x); }
// z pre-scaled by -log2e:  sigmoid(z0) = 1/(1+2^z)
__device__ __forceinline__ float sig2(float z)  { return frcp(1.0f + __builtin_amdgcn_exp2f(z)); }
// z pre-scaled by +2log2e: tanh(z0) = 1 - 2/(1+2^z)
__device__ __forceinline__ float tanh2(float z) { return 1.0f - 2.0f * frcp(1.0f + __builtin_amdgcn_exp2f(z)); }

#define MFMA(A, B, C) __builtin_amdgcn_mfma_f32_16x16x32_f16((A), (B), (C), 0, 0, 0)

// ---------------------------------------------------------------------------
// Sense-reversing grid barrier (r12-verified correct). bar[0]=count,
// bar[1]=generation. Agent-scope ACQ_REL arrival publishes this block's
// global stores (L2 writeback); acquire spin invalidates for the reader.
// __syncthreads drains vmcnt before thread 0 arrives.
// ---------------------------------------------------------------------------
__device__ __forceinline__ void grid_barrier(unsigned* bar) {
    __syncthreads();
    if (threadIdx.x == 0) {
        const unsigned gen =
            __hip_atomic_load(&bar[1], __ATOMIC_RELAXED, __HIP_MEMORY_SCOPE_AGENT);
        const unsigned old =
            __hip_atomic_fetch_add(&bar[0], 1u, __ATOMIC_ACQ_REL, __HIP_MEMORY_SCOPE_AGENT);
        if (old == NBLK - 1u) {
            __hip_atomic_store(&bar[0], 0u, __ATOMIC_RELAXED, __HIP_MEMORY_SCOPE_AGENT);
            __hip_atomic_store(&bar[1], gen + 1u, __ATOMIC_RELEASE, __HIP_MEMORY_SCOPE_AGENT);
        } else {
            while (__hip_atomic_load(&bar[1], __ATOMIC_ACQUIRE,
                                     __HIP_MEMORY_SCOPE_AGENT) == gen) {
                __builtin_amdgcn_s_sleep(2);
            }
        }
    }
    __syncthreads();
}

// ---------------------------------------------------------------------------
// Setup: 16 B-fragments, activation scale folded per column (see r12 notes).
// Also zero-inits the grid-barrier words (self-resetting across replays).
// ---------------------------------------------------------------------------
__global__ void build_frags(const float* __restrict__ wk,
                            const float* __restrict__ wr,
                            _Float16* __restrict__ blob,
                            unsigned* __restrict__ bar) {
    if (threadIdx.x == 0) { bar[0] = 0u; bar[1] = 0u; }
    const int lane = threadIdx.x & 63;
    const int quad = lane >> 4, nlo = lane & 15;
    for (int chunk = 0; chunk < 5; ++chunk) {
        for (int nh = 0; nh < 2; ++nh) {
            const int n = nh * 16 + nlo;
            const float scale = (n >= 16 && n < 24) ? (2.0f * LOG2E) : (-LOG2E);
            const int frag = chunk * 2 + nh;
            _Float16* dhi = blob + ((size_t)frag * 64 + lane) * 8;
            _Float16* dlo = (chunk >= 2)
                ? blob + ((size_t)(10 + (chunk - 2) * 2 + nh) * 64 + lane) * 8
                : nullptr;
            for (int j = 0; j < 8; ++j) {
                const int k = quad * 8 + j;
                float w = 0.0f;
                if (chunk == 0) {
                    int tap = k >> 2, ci = k & 3;
                    if (ci < 3) w = wk[(tap * 3 + ci) * GG + n];
                } else if (chunk == 1) {
                    if (quad == 0 && j < 3) w = wk[(8 * 3 + j) * GG + n];
                } else {
                    int c = chunk - 2;
                    int tap = c * 4 + quad, ci = j;
                    if (tap < 9) w = wr[(tap * FF + ci) * GG + n];
                }
                w *= scale;
                _Float16 wh = (_Float16)w;
                dhi[j] = wh;
                if (dlo) dlo[j] = (_Float16)(w - (float)wh);
            }
        }
    }
}

// ---- slot helper macros (kept as macros so LDS stays ds_-addressed) ----
#define LOADX(TILE, XR, XIN)                                                  \
  {                                                                           \
    const int b_ = (TILE) >> 7, by_ = ((TILE) >> 3) & 15, bx_ = (TILE) & 7;   \
    _Pragma("unroll")                                                         \
    for (int k = 0; k < 3; ++k) {                                             \
      const int l = tid + k * 256;                                            \
      const bool in = (l < LH * LW);                                          \
      XIN[k] = in;                                                            \
      int r = l / LW, c = l - r * LW;                                         \
      int gy = by_ * THT + r - 1, gx = bx_ * TW + c - 1;                      \
      const bool inb = in && (unsigned)gy < HH && (unsigned)gx < WW;          \
      const float* p = xg + (((size_t)(b_ * TT + t) * HH + gy) * WW + gx) * CIN; \
      XR[k][0] = inb ? p[0] : 0.0f;                                           \
      XR[k][1] = inb ? p[1] : 0.0f;                                           \
      XR[k][2] = inb ? p[2] : 0.0f;                                           \
    }                                                                         \
  }

#define LOADH(TILE, HR)                                                       \
  {                                                                           \
    const int b_ = (TILE) >> 7, by_ = ((TILE) >> 3) & 15, bx_ = (TILE) & 7;   \
    _Pragma("unroll")                                                         \
    for (int k = 0; k < 3; ++k) {                                             \
      const int l = tid + k * 256;                                            \
      const bool in = (l < LH * LW);                                          \
      int r = l / LW, c = l - r * LW;                                         \
      int gy = by_ * THT + r - 1, gx = bx_ * TW + c - 1;                      \
      const bool inb = in && (unsigned)gy < HH && (unsigned)gx < WW;          \
      half8 v = {(_Float16)0, (_Float16)0, (_Float16)0, (_Float16)0,          \
                 (_Float16)0, (_Float16)0, (_Float16)0, (_Float16)0};         \
      if (inb) v = *(const half8*)(hin + ((size_t)(b_ * HH + gy) * WW + gx) * FF); \
      HR[k] = v;                                                              \
    }                                                                         \
  }

#define WRITELDS(XR, XIN, HR, DOH)                                            \
  {                                                                           \
    _Pragma("unroll")                                                         \
    for (int k = 0; k < 3; ++k) {                                             \
      if (XIN[k]) {                                                           \
        half4 vh;                                                             \
        vh.x = (_Float16)XR[k][0];                                            \
        vh.y = (_Float16)XR[k][1];                                            \
        vh.z = (_Float16)XR[k][2];                                            \
        vh.w = (_Float16)0;                                                   \
        xls[tid + k * 256] = vh;                                              \
        if (DOH) hls[tid + k * 256] = HR[k];                                  \
      }                                                                       \
    }                                                                         \
  }

// ---------------------------------------------------------------------------
// Persistent kernel: all TT timesteps, grid barrier between them.
// Block = 256 thr (4 waves); block owns 2 tiles, software-pipelined.
// c state: LDS resident for whole run. h: global fp16 ping-pong (halo).
// ---------------------------------------------------------------------------
__global__ __launch_bounds__(256, 4) void lstm_all(
    const float* __restrict__ xg,       // [B,T,H,W,3] fp32
    const _Float16* __restrict__ blob,  // scaled B-fragments (hi 0..9, lo 10..15)
    const float* __restrict__ bias,     // [32] (unscaled; scaled here)
    _Float16* __restrict__ h0,          // ping-pong h buffers
    _Float16* __restrict__ h1,
    unsigned* __restrict__ bar,         // grid barrier state
    const float* __restrict__ gamma, const float* __restrict__ beta,
    const float* __restrict__ mean,  const float* __restrict__ var,
    const float* __restrict__ dw,    const float* __restrict__ db,
    float* __restrict__ out)            // [B,H,W,2]
{
    __shared__ half8  hls[LH * LW];             // h tile + halo (9792 B)
    __shared__ half4  xls[LH * LW];             // x tile + halo (4896 B)
    __shared__ half2t cls[SLOTS * 4 * NG * 64]; // c state, 16 KB, lane-private

    const int tid  = threadIdx.x;
    const int lane = tid & 63, wave = tid >> 6;
    const int quad = lane >> 4, nlo = lane & 15;
    const bool lo8 = (nlo < 8);
    const int fc = nlo & 7;

    // B-fragments once for the whole run (L2-hot, 16 x 16B per lane)
    half8 bfh[10], bfl[6];
#pragma unroll
    for (int i = 0; i < 10; ++i)
        bfh[i] = *(const half8*)(blob + ((size_t)i * 64 + lane) * 8);
#pragma unroll
    for (int i = 0; i < 6; ++i)
        bfl[i] = *(const half8*)(blob + ((size_t)(10 + i) * 64 + lane) * 8);

    // bias, activation-scale folded (cols 16..23 are the g gate)
    const float bv0 = bias[nlo] * (-LOG2E);
    const float bv1 = bias[16 + nlo] * (lo8 ? 2.0f * LOG2E : -LOG2E);

    // fused-epilogue constants (used at t = TT-1)
    const float bn_s = gamma[fc] * rsqrtf(var[fc] + 1e-3f);
    const float bn_b = beta[fc] - mean[fc] * bn_s;
    const float dw0 = dw[fc * 2 + 0], dw1 = dw[fc * 2 + 1];
    const float db0 = db[0], db1 = db[1];

#define COMPUTE(SL, TILE)                                                     \
  {                                                                           \
    const int b_ = (TILE) >> 7, by_ = ((TILE) >> 3) & 15, bx_ = (TILE) & 7;   \
    _Pragma("unroll")                                                         \
    for (int g = 0; g < NG; ++g) {                                            \
      const int lr  = wave * 4 + (g >> 1);                                    \
      const int gx0 = (g & 1) * 16;                                           \
      const int lc  = gx0 + nlo;                                              \
      const int t0 = 2 * quad, t1 = t0 + 1;                                   \
      half4 p  = xls[(lr + t0 / 3) * LW + lc + t0 % 3];                       \
      half4 q  = xls[(lr + t1 / 3) * LW + lc + t1 % 3];                       \
      half4 s8 = xls[(lr + 2) * LW + lc + 2];                                 \
      half8 a_xA = (half8){p.x, p.y, p.z, p.w, q.x, q.y, q.z, q.w};           \
      half8 a_xB = (half8){s8.x, s8.y, s8.z, s8.w, s8.x, s8.y, s8.z, s8.w};   \
      floatx4 acc0 = {bv0, bv0, bv0, bv0};                                    \
      floatx4 acc1 = {bv1, bv1, bv1, bv1};                                    \
      acc0 = MFMA(a_xA, bfh[0], acc0);  acc1 = MFMA(a_xA, bfh[1], acc1);      \
      acc0 = MFMA(a_xB, bfh[2], acc0);  acc1 = MFMA(a_xB, bfh[3], acc1);      \
      if (!first) {                                                           \
        _Pragma("unroll")                                                     \
        for (int c = 0; c < 3; ++c) {                                         \
          int tap = c * 4 + quad;                                             \
          if (tap > 8) tap = 8;                                               \
          half8 ah = hls[(lr + tap / 3) * LW + lc + tap % 3];                 \
          acc0 = MFMA(ah, bfh[4 + c * 2], acc0);                              \
          acc1 = MFMA(ah, bfh[5 + c * 2], acc1);                              \
          acc0 = MFMA(ah, bfl[c * 2 + 0], acc0);                              \
          acc1 = MFMA(ah, bfl[c * 2 + 1], acc1);                              \
        }                                                                     \
      }                                                                       \
      float s0 = lo8 ? acc0[2] : acc0[0]; float r0 = __shfl_xor(s0, 8, 64);   \
      float s1 = lo8 ? acc0[3] : acc0[1]; float r1 = __shfl_xor(s1, 8, 64);   \
      float s2 = lo8 ? acc1[2] : acc1[0]; float r2 = __shfl_xor(s2, 8, 64);   \
      float s3 = lo8 ? acc1[3] : acc1[1]; float r3 = __shfl_xor(s3, 8, 64);   \
      const float zi0 = lo8 ? acc0[0] : r0, zi1 = lo8 ? acc0[1] : r1;         \
      const float zf0 = lo8 ? r0 : acc0[2], zf1 = lo8 ? r1 : acc0[3];         \
      const float zg0 = lo8 ? acc1[0] : r2, zg1 = lo8 ? acc1[1] : r3;         \
      const float zo0 = lo8 ? r2 : acc1[2], zo1 = lo8 ? r3 : acc1[3];         \
      const int cidx = (((SL) * 4 + wave) * NG + g) * 64 + lane;              \
      float c0 = 0.f, c1 = 0.f;                                               \
      if (!first) {                                                           \
        half2t cp = cls[cidx];                                                \
        c0 = (float)cp.x; c1 = (float)cp.y;                                   \
      }                                                                       \
      const float ii0 = sig2(zi0), ff0 = sig2(zf0), gg0 = tanh2(zg0), oo0 = sig2(zo0); \
      const float cn0 = ff0 * c0 + ii0 * gg0;                                 \
      const float hn0 = oo0 * tanh2(cn0 * (2.0f * LOG2E));                    \
      const float ii1 = sig2(zi1), ff1 = sig2(zf1), gg1 = tanh2(zg1), oo1 = sig2(zo1); \
      const float cn1 = ff1 * c1 + ii1 * gg1;                                 \
      const float hn1 = oo1 * tanh2(cn1 * (2.0f * LOG2E));                    \
      const int m0 = quad * 4 + (lo8 ? 0 : 2);                                \
      const int gy = by_ * THT + lr;                                          \
      if (!last) {                                                            \
        half2t cc; cc.x = (_Float16)cn0; cc.y = (_Float16)cn1;                \
        cls[cidx] = cc;                                                       \
        _Float16* hp = hout + ((size_t)(b_ * HH + gy) * WW + bx_ * TW + gx0 + m0) * FF + fc; \
        hp[0]  = (_Float16)hn0;                                               \
        hp[FF] = (_Float16)hn1;                                               \
      } else {                                                                \
        float y0 = bn_s * hn0 + bn_b; y0 = (y0 >= 0.f) ? y0 : 0.3f * y0;      \
        float y1 = bn_s * hn1 + bn_b; y1 = (y1 >= 0.f) ? y1 : 0.3f * y1;      \
        float p00 = y0 * dw0, p01 = y0 * dw1;                                 \
        float p10 = y1 * dw0, p11 = y1 * dw1;                                 \
        _Pragma("unroll")                                                     \
        for (int m = 1; m <= 4; m <<= 1) {                                    \
          p00 += __shfl_xor(p00, m, 64);                                      \
          p01 += __shfl_xor(p01, m, 64);                                      \
          p10 += __shfl_xor(p10, m, 64);                                      \
          p11 += __shfl_xor(p11, m, 64);                                      \
        }                                                                     \
        const int j = nlo & 7;                                                \
        if (j < 4) {                                                          \
          const int px = m0 + (j >> 1);                                       \
          const int k  = j & 1;                                               \
          float val = (j == 0 ? p00 : j == 1 ? p01 : j == 2 ? p10 : p11)      \
                      + (k ? db1 : db0);                                      \
          out[((size_t)(b_ * HH + gy) * WW + bx_ * TW + gx0 + px) * 2 + k] = val; \
        }                                                                     \
      }                                                                       \
    }                                                                         \
  }

    const int tile0 = (int)blockIdx.x;
    const int tile1 = (int)blockIdx.x + NBLK;

#pragma unroll 1
    for (int t = 0; t < TT; ++t) {
        const _Float16* hin  = (t & 1) ? h1 : h0;
        _Float16*       hout = (t & 1) ? h0 : h1;
        const bool first = (t == 0);
        const bool last  = (t == TT - 1);

        // ---- slot0 loads (post-barrier: h(t-1) now globally visible) ----
        float xr0[3][3]; bool xin0[3]; half8 hr0[3];
        LOADX(tile0, xr0, xin0);
        if (!first) LOADH(tile0, hr0);

        // ---- slot1 loads issued early: latency hides under slot0 work ----
        float xr1[3][3]; bool xin1[3]; half8 hr1[3];
        LOADX(tile1, xr1, xin1);
        if (!first) LOADH(tile1, hr1);

        // ---- stage + compute slot0 (LDS free: barrier/entry synced) ----
        WRITELDS(xr0, xin0, hr0, !first);
        __syncthreads();
        COMPUTE(0, tile0);
        __syncthreads();

        // ---- stage + compute slot1 ----
        WRITELDS(xr1, xin1, hr1, !first);
        __syncthreads();
        COMPUTE(1, tile1);

        if (t < TT - 1) grid_barrier(bar);
    }
#undef COMPUTE
}

extern "C" void kernel_launch(void* const* d_in, const int* in_sizes, int n_in,
                              void* d_out, int out_size, void* d_ws, size_t ws_size,
                              hipStream_t stream) {
    const float* x     = (const float*)d_in[0];
    const float* wk    = (const float*)d_in[1];
    const float* wr    = (const float*)d_in[2];
    const float* bias  = (const float*)d_in[3];
    const float* gamma = (const float*)d_in[4];
    const float* beta  = (const float*)d_in[5];
    const float* mean  = (const float*)d_in[6];
    const float* var   = (const float*)d_in[7];
    const float* dw    = (const float*)d_in[8];
    const float* db    = (const float*)d_in[9];
    float* out = (float*)d_out;

    // ws: blob 32KB | bar 256B | h0 fp16 16.78MB | h1 fp16 16.78MB
    const size_t state = (size_t)BB * HH * WW * FF;
    _Float16* blob = (_Float16*)d_ws;
    unsigned* bar  = (unsigned*)((char*)d_ws + 32768);
    _Float16* h0   = (_Float16*)((char*)d_ws + 32768 + 256);
    _Float16* h1   = h0 + state;

    build_frags<<<1, 64, 0, stream>>>(wk, wr, blob, bar);

    lstm_all<<<dim3(NBLK), dim3(256), 0, stream>>>(
        x, blob, bias, h0, h1, bar,
        gamma, beta, mean, var, dw, db, out);
}

// Round 5
// 531.086 us; speedup vs baseline: 1.7896x; 1.7896x over previous
//
#include <hip/hip_runtime.h>

// ConvLSTM2D (B=16,T=5,H=W=256,Cin=3,F=8) + BN + LeakyReLU + Dense(8->2)
// Round-14: r12 shell (512 blocks, 2/CU, SLOTS=4, 92 VGPR no-spill, 176MB
// traffic verified) + SLOT SOFTWARE PIPELINE via ping-pong register buffers.
// r13's launch_bounds(256,4) spilled (VGPR 64, +436MB scratch traffic, 950us)
// -> keep cap 256 (2 blocks/CU, LDS-limited anyway) and hide HBM latency with
// ILP: slot sl+1's x/h loads issue before slot sl's compute; at sl=3 the next
// timestep's slot-0 x prefetches across the grid barrier. +21 VGPR only.

#define BB  16
#define TT  5
#define HH  256
#define WW  256
#define CIN 3
#define FF  8
#define GG  32

#define TW  32   // tile width (pixels)
#define THT 16   // tile height
#define LW  34   // TW+2 halo
#define LH  18   // THT+2 halo
#define NG  8    // 16x16-px groups per wave

#define NBLK  512   // persistent blocks (2 per CU, LDS-limited)
#define SLOTS 4     // tiles per block = 2048/NBLK

#define LOG2E 1.44269504088896340736f

typedef _Float16 half8  __attribute__((ext_vector_type(8)));
typedef _Float16 half4  __attribute__((ext_vector_type(4)));
typedef _Float16 half2t __attribute__((ext_vector_type(2)));
typedef float    floatx4 __attribute__((ext_vector_type(4)));

__device__ __forceinline__ float frcp(float x) { return __builtin_amdgcn_rcpf(x); }
// z pre-scaled by -log2e:  sigmoid(z0) = 1/(1+2^z)
__device__ __forceinline__ float sig2(float z)  { return frcp(1.0f + __builtin_amdgcn_exp2f(z)); }
// z pre-scaled by +2log2e: tanh(z0) = 1 - 2/(1+2^z)
__device__ __forceinline__ float tanh2(float z) { return 1.0f - 2.0f * frcp(1.0f + __builtin_amdgcn_exp2f(z)); }

#define MFMA(A, B, C) __builtin_amdgcn_mfma_f32_16x16x32_f16((A), (B), (C), 0, 0, 0)

// ---------------------------------------------------------------------------
// Sense-reversing grid barrier (r12-verified). bar[0]=count, bar[1]=gen.
// ---------------------------------------------------------------------------
__device__ __forceinline__ void grid_barrier(unsigned* bar) {
    __syncthreads();
    if (threadIdx.x == 0) {
        const unsigned gen =
            __hip_atomic_load(&bar[1], __ATOMIC_RELAXED, __HIP_MEMORY_SCOPE_AGENT);
        const unsigned old =
            __hip_atomic_fetch_add(&bar[0], 1u, __ATOMIC_ACQ_REL, __HIP_MEMORY_SCOPE_AGENT);
        if (old == NBLK - 1u) {
            __hip_atomic_store(&bar[0], 0u, __ATOMIC_RELAXED, __HIP_MEMORY_SCOPE_AGENT);
            __hip_atomic_store(&bar[1], gen + 1u, __ATOMIC_RELEASE, __HIP_MEMORY_SCOPE_AGENT);
        } else {
            while (__hip_atomic_load(&bar[1], __ATOMIC_ACQUIRE,
                                     __HIP_MEMORY_SCOPE_AGENT) == gen) {
                __builtin_amdgcn_s_sleep(2);
            }
        }
    }
    __syncthreads();
}

// ---------------------------------------------------------------------------
// Setup: 16 B-fragments (see r12 notes). Also zero-inits barrier words.
// ---------------------------------------------------------------------------
__global__ void build_frags(const float* __restrict__ wk,
                            const float* __restrict__ wr,
                            _Float16* __restrict__ blob,
                            unsigned* __restrict__ bar) {
    if (threadIdx.x == 0) { bar[0] = 0u; bar[1] = 0u; }
    const int lane = threadIdx.x & 63;
    const int quad = lane >> 4, nlo = lane & 15;
    for (int chunk = 0; chunk < 5; ++chunk) {
        for (int nh = 0; nh < 2; ++nh) {
            const int n = nh * 16 + nlo;
            const float scale = (n >= 16 && n < 24) ? (2.0f * LOG2E) : (-LOG2E);
            const int frag = chunk * 2 + nh;
            _Float16* dhi = blob + ((size_t)frag * 64 + lane) * 8;
            _Float16* dlo = (chunk >= 2)
                ? blob + ((size_t)(10 + (chunk - 2) * 2 + nh) * 64 + lane) * 8
                : nullptr;
            for (int j = 0; j < 8; ++j) {
                const int k = quad * 8 + j;
                float w = 0.0f;
                if (chunk == 0) {
                    int tap = k >> 2, ci = k & 3;
                    if (ci < 3) w = wk[(tap * 3 + ci) * GG + n];
                } else if (chunk == 1) {
                    if (quad == 0 && j < 3) w = wk[(8 * 3 + j) * GG + n];
                } else {
                    int c = chunk - 2;
                    int tap = c * 4 + quad, ci = j;
                    if (tap < 9) w = wr[(tap * FF + ci) * GG + n];
                }
                w *= scale;
                _Float16 wh = (_Float16)w;
                dhi[j] = wh;
                if (dlo) dlo[j] = (_Float16)(w - (float)wh);
            }
        }
    }
}

// ---- staging helper macros ----
#define LOADX(TILE, T, XR, XIN)                                               \
  {                                                                           \
    const int b_ = (TILE) >> 7, by_ = ((TILE) >> 3) & 15, bx_ = (TILE) & 7;   \
    _Pragma("unroll")                                                         \
    for (int k = 0; k < 3; ++k) {                                             \
      const int l = tid + k * 256;                                            \
      const bool in = (l < LH * LW);                                          \
      XIN[k] = in;                                                            \
      int r = l / LW, c = l - r * LW;                                         \
      int gy = by_ * THT + r - 1, gx = bx_ * TW + c - 1;                      \
      const bool inb = in && (unsigned)gy < HH && (unsigned)gx < WW;          \
      const float* p = xg + (((size_t)(b_ * TT + (T)) * HH + gy) * WW + gx) * CIN; \
      XR[k][0] = inb ? p[0] : 0.0f;                                           \
      XR[k][1] = inb ? p[1] : 0.0f;                                           \
      XR[k][2] = inb ? p[2] : 0.0f;                                           \
    }                                                                         \
  }

#define LOADH(TILE, HR)                                                       \
  {                                                                           \
    const int b_ = (TILE) >> 7, by_ = ((TILE) >> 3) & 15, bx_ = (TILE) & 7;   \
    _Pragma("unroll")                                                         \
    for (int k = 0; k < 3; ++k) {                                             \
      const int l = tid + k * 256;                                            \
      const bool in = (l < LH * LW);                                          \
      int r = l / LW, c = l - r * LW;                                         \
      int gy = by_ * THT + r - 1, gx = bx_ * TW + c - 1;                      \
      const bool inb = in && (unsigned)gy < HH && (unsigned)gx < WW;          \
      half8 v = {(_Float16)0, (_Float16)0, (_Float16)0, (_Float16)0,          \
                 (_Float16)0, (_Float16)0, (_Float16)0, (_Float16)0};         \
      if (inb) v = *(const half8*)(hin + ((size_t)(b_ * HH + gy) * WW + gx) * FF); \
      HR[k] = v;                                                              \
    }                                                                         \
  }

#define WRITELDS(XR, XIN, HR, DOH)                                            \
  {                                                                           \
    _Pragma("unroll")                                                         \
    for (int k = 0; k < 3; ++k) {                                             \
      if (XIN[k]) {                                                           \
        half4 vh;                                                             \
        vh.x = (_Float16)XR[k][0];                                            \
        vh.y = (_Float16)XR[k][1];                                            \
        vh.z = (_Float16)XR[k][2];                                            \
        vh.w = (_Float16)0;                                                   \
        xls[tid + k * 256] = vh;                                              \
        if (DOH) hls[tid + k * 256] = HR[k];                                  \
      }                                                                       \
    }                                                                         \
  }

// ---------------------------------------------------------------------------
// Persistent kernel: all TT timesteps, grid barrier between them.
// Block = 256 thr (4 waves); owns 4 tiles, slot loop software-pipelined:
// slot sl+1's global loads fly during slot sl's compute.
// c state: LDS resident for whole run. h: global fp16 ping-pong (halo).
// ---------------------------------------------------------------------------
__global__ __launch_bounds__(256, 2) void lstm_all(
    const float* __restrict__ xg,       // [B,T,H,W,3] fp32
    const _Float16* __restrict__ blob,  // scaled B-fragments (hi 0..9, lo 10..15)
    const float* __restrict__ bias,     // [32] (unscaled; scaled here)
    _Float16* __restrict__ h0,          // ping-pong h buffers
    _Float16* __restrict__ h1,
    unsigned* __restrict__ bar,         // grid barrier state
    const float* __restrict__ gamma, const float* __restrict__ beta,
    const float* __restrict__ mean,  const float* __restrict__ var,
    const float* __restrict__ dw,    const float* __restrict__ db,
    float* __restrict__ out)            // [B,H,W,2]
{
    __shared__ half8  hls[LH * LW];             // h tile + halo (9792 B)
    __shared__ half4  xls[LH * LW];             // x tile + halo (4896 B)
    __shared__ half2t cls[SLOTS * 4 * NG * 64]; // c state, 32 KB, lane-private

    const int tid  = threadIdx.x;
    const int lane = tid & 63, wave = tid >> 6;
    const int quad = lane >> 4, nlo = lane & 15;
    const bool lo8 = (nlo < 8);
    const int fc = nlo & 7;

    // B-fragments once for the whole run (L2-hot, 16 x 16B per lane)
    half8 bfh[10], bfl[6];
#pragma unroll
    for (int i = 0; i < 10; ++i)
        bfh[i] = *(const half8*)(blob + ((size_t)i * 64 + lane) * 8);
#pragma unroll
    for (int i = 0; i < 6; ++i)
        bfl[i] = *(const half8*)(blob + ((size_t)(10 + i) * 64 + lane) * 8);

    // bias, activation-scale folded (cols 16..23 are the g gate)
    const float bv0 = bias[nlo] * (-LOG2E);
    const float bv1 = bias[16 + nlo] * (lo8 ? 2.0f * LOG2E : -LOG2E);

    // fused-epilogue constants (used at t = TT-1)
    const float bn_s = gamma[fc] * rsqrtf(var[fc] + 1e-3f);
    const float bn_b = beta[fc] - mean[fc] * bn_s;
    const float dw0 = dw[fc * 2 + 0], dw1 = dw[fc * 2 + 1];
    const float db0 = db[0], db1 = db[1];

#define COMPUTE(SL, TILE)                                                     \
  {                                                                           \
    const int b_ = (TILE) >> 7, by_ = ((TILE) >> 3) & 15, bx_ = (TILE) & 7;   \
    _Pragma("unroll")                                                         \
    for (int g = 0; g < NG; ++g) {                                            \
      const int lr  = wave * 4 + (g >> 1);                                    \
      const int gx0 = (g & 1) * 16;                                           \
      const int lc  = gx0 + nlo;                                              \
      const int t0 = 2 * quad, t1 = t0 + 1;                                   \
      half4 p  = xls[(lr + t0 / 3) * LW + lc + t0 % 3];                       \
      half4 q  = xls[(lr + t1 / 3) * LW + lc + t1 % 3];                       \
      half4 s8 = xls[(lr + 2) * LW + lc + 2];                                 \
      half8 a_xA = (half8){p.x, p.y, p.z, p.w, q.x, q.y, q.z, q.w};           \
      half8 a_xB = (half8){s8.x, s8.y, s8.z, s8.w, s8.x, s8.y, s8.z, s8.w};   \
      floatx4 acc0 = {bv0, bv0, bv0, bv0};                                    \
      floatx4 acc1 = {bv1, bv1, bv1, bv1};                                    \
      acc0 = MFMA(a_xA, bfh[0], acc0);  acc1 = MFMA(a_xA, bfh[1], acc1);      \
      acc0 = MFMA(a_xB, bfh[2], acc0);  acc1 = MFMA(a_xB, bfh[3], acc1);      \
      if (!first) {                                                           \
        _Pragma("unroll")                                                     \
        for (int c = 0; c < 3; ++c) {                                         \
          int tap = c * 4 + quad;                                             \
          if (tap > 8) tap = 8;                                               \
          half8 ah = hls[(lr + tap / 3) * LW + lc + tap % 3];                 \
          acc0 = MFMA(ah, bfh[4 + c * 2], acc0);                              \
          acc1 = MFMA(ah, bfh[5 + c * 2], acc1);                              \
          acc0 = MFMA(ah, bfl[c * 2 + 0], acc0);                              \
          acc1 = MFMA(ah, bfl[c * 2 + 1], acc1);                              \
        }                                                                     \
      }                                                                       \
      float s0 = lo8 ? acc0[2] : acc0[0]; float r0 = __shfl_xor(s0, 8, 64);   \
      float s1 = lo8 ? acc0[3] : acc0[1]; float r1 = __shfl_xor(s1, 8, 64);   \
      float s2 = lo8 ? acc1[2] : acc1[0]; float r2 = __shfl_xor(s2, 8, 64);   \
      float s3 = lo8 ? acc1[3] : acc1[1]; float r3 = __shfl_xor(s3, 8, 64);   \
      const float zi0 = lo8 ? acc0[0] : r0, zi1 = lo8 ? acc0[1] : r1;         \
      const float zf0 = lo8 ? r0 : acc0[2], zf1 = lo8 ? r1 : acc0[3];         \
      const float zg0 = lo8 ? acc1[0] : r2, zg1 = lo8 ? acc1[1] : r3;         \
      const float zo0 = lo8 ? r2 : acc1[2], zo1 = lo8 ? r3 : acc1[3];         \
      const int cidx = (((SL) * 4 + wave) * NG + g) * 64 + lane;              \
      float c0 = 0.f, c1 = 0.f;                                               \
      if (!first) {                                                           \
        half2t cp = cls[cidx];                                                \
        c0 = (float)cp.x; c1 = (float)cp.y;                                   \
      }                                                                       \
      const float ii0 = sig2(zi0), ff0 = sig2(zf0), gg0 = tanh2(zg0), oo0 = sig2(zo0); \
      const float cn0 = ff0 * c0 + ii0 * gg0;                                 \
      const float hn0 = oo0 * tanh2(cn0 * (2.0f * LOG2E));                    \
      const float ii1 = sig2(zi1), ff1 = sig2(zf1), gg1 = tanh2(zg1), oo1 = sig2(zo1); \
      const float cn1 = ff1 * c1 + ii1 * gg1;                                 \
      const float hn1 = oo1 * tanh2(cn1 * (2.0f * LOG2E));                    \
      const int m0 = quad * 4 + (lo8 ? 0 : 2);                                \
      const int gy = by_ * THT + lr;                                          \
      if (!last) {                                                            \
        half2t cc; cc.x = (_Float16)cn0; cc.y = (_Float16)cn1;                \
        cls[cidx] = cc;                                                       \
        _Float16* hp = hout + ((size_t)(b_ * HH + gy) * WW + bx_ * TW + gx0 + m0) * FF + fc; \
        hp[0]  = (_Float16)hn0;                                               \
        hp[FF] = (_Float16)hn1;                                               \
      } else {                                                                \
        float y0 = bn_s * hn0 + bn_b; y0 = (y0 >= 0.f) ? y0 : 0.3f * y0;      \
        float y1 = bn_s * hn1 + bn_b; y1 = (y1 >= 0.f) ? y1 : 0.3f * y1;      \
        float p00 = y0 * dw0, p01 = y0 * dw1;                                 \
        float p10 = y1 * dw0, p11 = y1 * dw1;                                 \
        _Pragma("unroll")                                                     \
        for (int m = 1; m <= 4; m <<= 1) {                                    \
          p00 += __shfl_xor(p00, m, 64);                                      \
          p01 += __shfl_xor(p01, m, 64);                                      \
          p10 += __shfl_xor(p10, m, 64);                                      \
          p11 += __shfl_xor(p11, m, 64);                                      \
        }                                                                     \
        const int j = nlo & 7;                                                \
        if (j < 4) {                                                          \
          const int px = m0 + (j >> 1);                                       \
          const int k  = j & 1;                                               \
          float val = (j == 0 ? p00 : j == 1 ? p01 : j == 2 ? p10 : p11)      \
                      + (k ? db1 : db0);                                      \
          out[((size_t)(b_ * HH + gy) * WW + bx_ * TW + gx0 + px) * 2 + k] = val; \
        }                                                                     \
      }                                                                       \
    }                                                                         \
  }

    // ping-pong register staging buffers: slot sl uses parity sl&1
    float xr[2][3][3];
    bool  xin[2][3];
    half8 hr[2][3];

    // prologue: x for (t=0, slot0)
    LOADX((int)blockIdx.x, 0, xr[0], xin[0]);

#pragma unroll 1
    for (int t = 0; t < TT; ++t) {
        const _Float16* hin  = (t & 1) ? h1 : h0;
        _Float16*       hout = (t & 1) ? h0 : h1;
        const bool first = (t == 0);
        const bool last  = (t == TT - 1);

        // h for slot0 (x already prefetched into xr[0] across the barrier)
        if (!first) LOADH((int)blockIdx.x, hr[0]);

#pragma unroll
        for (int sl = 0; sl < SLOTS; ++sl) {
            const int pb   = sl & 1;
            const int tile = (int)blockIdx.x + sl * NBLK;

            // stage current slot to LDS (prev compute done: loop-end barrier)
            WRITELDS(xr[pb], xin[pb], hr[pb], !first);

            // prefetch next slot (or next timestep's slot0 x) -> in flight
            // across the pre-compute barrier + COMPUTE (+ grid barrier)
            if (sl < SLOTS - 1) {
                LOADX(tile + NBLK, t, xr[pb ^ 1], xin[pb ^ 1]);
                if (!first) LOADH(tile + NBLK, hr[pb ^ 1]);
            } else if (!last) {
                LOADX((int)blockIdx.x, t + 1, xr[pb ^ 1], xin[pb ^ 1]);
            }

            __syncthreads();
            COMPUTE(sl, tile);
            __syncthreads();
        }

        if (t < TT - 1) grid_barrier(bar);
    }
#undef COMPUTE
}

extern "C" void kernel_launch(void* const* d_in, const int* in_sizes, int n_in,
                              void* d_out, int out_size, void* d_ws, size_t ws_size,
                              hipStream_t stream) {
    const float* x     = (const float*)d_in[0];
    const float* wk    = (const float*)d_in[1];
    const float* wr    = (const float*)d_in[2];
    const float* bias  = (const float*)d_in[3];
    const float* gamma = (const float*)d_in[4];
    const float* beta  = (const float*)d_in[5];
    const float* mean  = (const float*)d_in[6];
    const float* var   = (const float*)d_in[7];
    const float* dw    = (const float*)d_in[8];
    const float* db    = (const float*)d_in[9];
    float* out = (float*)d_out;

    // ws: blob 32KB | bar 256B | h0 fp16 16.78MB | h1 fp16 16.78MB
    const size_t state = (size_t)BB * HH * WW * FF;
    _Float16* blob = (_Float16*)d_ws;
    unsigned* bar  = (unsigned*)((char*)d_ws + 32768);
    _Float16* h0   = (_Float16*)((char*)d_ws + 32768 + 256);
    _Float16* h1   = h0 + state;

    build_frags<<<1, 64, 0, stream>>>(wk, wr, blob, bar);

    lstm_all<<<dim3(NBLK), dim3(256), 0, stream>>>(
        x, blob, bias, h0, h1, bar,
        gamma, beta, mean, var, dw, db, out);
}

// Round 7
// 292.372 us; speedup vs baseline: 3.2508x; 1.8165x over previous
//
#include <hip/hip_runtime.h>

// ConvLSTM2D (B=16,T=5,H=W=256,Cin=3,F=8) + BN + LeakyReLU + Dense(8->2)
// Round-16: identical to r15 (never executed — broker timeout).
// TEMPORAL PAIR FUSION, multi-launch. Persistent-kernel arc (r12-r14:
// 432/950/531us) abandoned — 2 blocks/CU can't hide latency, reg fixes spill.
// Multi-launch skeleton (255us baseline), fusing 2 timesteps per launch with
// 2px-overlapped tiles (stride 30x14, grid 9x19x16=2736): h(t) lives only in
// LDS (never HBM), c(t) in regs, h/c traffic ~halved, launches 5->3. c in
// plain [b,y,x,ch] fp16 layout (coalesced u16 lanes), double-buffered across
// launches. Numerics identical to r9 (same fp16 rounding points).
// Workspace: 32KB blob + 4 x 16.78MB state = 67.2MB.

#define BB  16
#define TT  5
#define HH  256
#define WW  256
#define CIN 3
#define FF  8
#define GG  32

#define TW  32   // computed tile width
#define THT 16   // computed tile height
#define LW  34   // TW+2 halo
#define LH  18   // THT+2 halo
#define NG  8    // 16x16-px groups per wave

#define SW  30   // pair-kernel interior stride x (TW-2)
#define SH  14   // pair-kernel interior stride y (THT-2)
#define NPX 9    // ceil(256/30)
#define NPY 19   // ceil(256/14)

#define LOG2E 1.44269504088896340736f

typedef _Float16 half8  __attribute__((ext_vector_type(8)));
typedef _Float16 half4  __attribute__((ext_vector_type(4)));
typedef _Float16 half2t __attribute__((ext_vector_type(2)));
typedef float    floatx4 __attribute__((ext_vector_type(4)));

__device__ __forceinline__ float frcp(float x) { return __builtin_amdgcn_rcpf(x); }
// z pre-scaled by -log2e:  sigmoid(z0) = 1/(1+2^z)
__device__ __forceinline__ float sig2(float z)  { return frcp(1.0f + __builtin_amdgcn_exp2f(z)); }
// z pre-scaled by +2log2e: tanh(z0) = 1 - 2/(1+2^z)
__device__ __forceinline__ float tanh2(float z) { return 1.0f - 2.0f * frcp(1.0f + __builtin_amdgcn_exp2f(z)); }

__device__ __forceinline__ int clampi(int v, int lo, int hi) {
    return v < lo ? lo : (v > hi ? hi : v);
}

#define MFMA(A, B, C) __builtin_amdgcn_mfma_f32_16x16x32_f16((A), (B), (C), 0, 0, 0)

// Gate phase (verbatim r9 logic). Inputs: acc0/acc1 MFMA accs, c0/c1 prior
// cell state for pixels m0,m0+1. Outputs cn*/hn* fp32.
#define GATES(ACC0, ACC1, C0, C1, CN0, CN1, HN0, HN1)                         \
  float CN0, CN1, HN0, HN1;                                                   \
  {                                                                           \
    float s0 = lo8 ? ACC0[2] : ACC0[0]; float r0 = __shfl_xor(s0, 8, 64);     \
    float s1 = lo8 ? ACC0[3] : ACC0[1]; float r1 = __shfl_xor(s1, 8, 64);     \
    float s2 = lo8 ? ACC1[2] : ACC1[0]; float r2 = __shfl_xor(s2, 8, 64);     \
    float s3 = lo8 ? ACC1[3] : ACC1[1]; float r3 = __shfl_xor(s3, 8, 64);     \
    const float zi0 = lo8 ? ACC0[0] : r0, zi1 = lo8 ? ACC0[1] : r1;           \
    const float zf0 = lo8 ? r0 : ACC0[2], zf1 = lo8 ? r1 : ACC0[3];           \
    const float zg0 = lo8 ? ACC1[0] : r2, zg1 = lo8 ? ACC1[1] : r3;           \
    const float zo0 = lo8 ? r2 : ACC1[2], zo1 = lo8 ? r3 : ACC1[3];           \
    const float ii0 = sig2(zi0), ff0 = sig2(zf0), gg0 = tanh2(zg0), oo0 = sig2(zo0); \
    CN0 = ff0 * (C0) + ii0 * gg0;                                             \
    HN0 = oo0 * tanh2(CN0 * (2.0f * LOG2E));                                  \
    const float ii1 = sig2(zi1), ff1 = sig2(zf1), gg1 = tanh2(zg1), oo1 = sig2(zo1); \
    CN1 = ff1 * (C1) + ii1 * gg1;                                             \
    HN1 = oo1 * tanh2(CN1 * (2.0f * LOG2E));                                  \
  }

// ---------------------------------------------------------------------------
// Setup: 16 B-fragments, activation scale folded per column:
// cols 0..15 (i,f) and 24..31 (o): *(-log2e); cols 16..23 (g): *(+2log2e).
// frag 0..9 = hi (chunks 0..4 x 2 col-halves); frag 10..15 = lo for h-conv
// chunks 2..4 (x-conv lo dropped). MFMA B layout: n = lane&15, k = quad*8+j.
// K-chunks: 0: x taps0-7 (k=tap*4+ci, ci padded to 4)
//           1: x tap8   (k=ci, only k<3 nonzero)
//           2..4: h taps [4c..4c+3] (k=(tap-4c)*8+ci), taps>8 zero
// ---------------------------------------------------------------------------
__global__ void build_frags(const float* __restrict__ wk,
                            const float* __restrict__ wr,
                            _Float16* __restrict__ blob) {
    const int lane = threadIdx.x & 63;
    const int quad = lane >> 4, nlo = lane & 15;
    for (int chunk = 0; chunk < 5; ++chunk) {
        for (int nh = 0; nh < 2; ++nh) {
            const int n = nh * 16 + nlo;
            const float scale = (n >= 16 && n < 24) ? (2.0f * LOG2E) : (-LOG2E);
            const int frag = chunk * 2 + nh;
            _Float16* dhi = blob + ((size_t)frag * 64 + lane) * 8;
            _Float16* dlo = (chunk >= 2)
                ? blob + ((size_t)(10 + (chunk - 2) * 2 + nh) * 64 + lane) * 8
                : nullptr;
            for (int j = 0; j < 8; ++j) {
                const int k = quad * 8 + j;
                float w = 0.0f;
                if (chunk == 0) {
                    int tap = k >> 2, ci = k & 3;
                    if (ci < 3) w = wk[(tap * 3 + ci) * GG + n];
                } else if (chunk == 1) {
                    if (quad == 0 && j < 3) w = wk[(8 * 3 + j) * GG + n];
                } else {
                    int c = chunk - 2;
                    int tap = c * 4 + quad, ci = j;
                    if (tap < 9) w = wr[(tap * FF + ci) * GG + n];
                }
                w *= scale;
                _Float16 wh = (_Float16)w;
                dhi[j] = wh;
                if (dlo) dlo[j] = (_Float16)(w - (float)wh);
            }
        }
    }
}

// ---------------------------------------------------------------------------
// Pair kernel: computes steps t and t+1. FIRSTPAIR=1 -> t=0 (no h/c input).
// Tile origin (x0,y0) = (bx*SW-1, by*SH-1); phase-1 computes full 32x16,
// phase-2 writes interior 30x14 (local rows 1..14, cols 1..30).
// ---------------------------------------------------------------------------
template <int FIRSTPAIR>
__global__ __launch_bounds__(256) void lstm_pair(
    const float* __restrict__ xg,       // [B,T,H,W,3] fp32
    int t,                              // first step of the pair
    const _Float16* __restrict__ blob,
    const float* __restrict__ bias,
    const _Float16* __restrict__ hin,   // h(t-1) plain [b,y,x,8] (unused if FIRSTPAIR)
    _Float16* __restrict__ hout,        // h(t+1) plain
    const _Float16* __restrict__ cin,   // c(t-1) plain (unused if FIRSTPAIR)
    _Float16* __restrict__ cout)        // c(t+1) plain
{
    __shared__ half8 hls1[LH * LW];                    // h(t-1) halo (9792 B)
    __shared__ half4 xls1[LH * LW];                    // x(t) halo   (4896 B)
    __shared__ half4 xls2[THT * TW];                   // x(t+1) tile (4096 B)
    __shared__ __align__(16) _Float16 hls2[THT * TW * FF]; // h(t) tile (8192 B)

    const int tid  = threadIdx.x;
    const int lane = tid & 63, wave = tid >> 6;
    const int quad = lane >> 4, nlo = lane & 15;
    const bool lo8 = (nlo < 8);
    const int fc = nlo & 7;
    const int m0 = quad * 4 + (lo8 ? 0 : 2);

    const int bx = blockIdx.x, by = blockIdx.y, b = blockIdx.z;
    const int x0 = bx * SW - 1, y0 = by * SH - 1;   // computed-tile origin

    // B-fragments (L2-hot)
    half8 bfh[10], bfl[6];
#pragma unroll
    for (int i = 0; i < 10; ++i)
        bfh[i] = *(const half8*)(blob + ((size_t)i * 64 + lane) * 8);
#pragma unroll
    for (int i = 0; i < 6; ++i)
        bfl[i] = *(const half8*)(blob + ((size_t)(10 + i) * 64 + lane) * 8);

    const float bv0 = bias[nlo] * (-LOG2E);
    const float bv1 = bias[16 + nlo] * (lo8 ? 2.0f * LOG2E : -LOG2E);

    // ================= PHASE A: issue ALL global loads =================
    // x(t) halo 34x18 (origin x0-1, y0-1)
    float xr1[3][3];
    bool  xin1[3];
#pragma unroll
    for (int k = 0; k < 3; ++k) {
        const int l = tid + k * 256;
        const bool in = (l < LH * LW);
        xin1[k] = in;
        int r = l / LW, c = l - r * LW;
        int gy = y0 - 1 + r, gx = x0 - 1 + c;
        const bool inb = in && (unsigned)gy < HH && (unsigned)gx < WW;
        const float* p = xg + (((size_t)(b * TT + t) * HH + gy) * WW + gx) * CIN;
        xr1[k][0] = inb ? p[0] : 0.0f;
        xr1[k][1] = inb ? p[1] : 0.0f;
        xr1[k][2] = inb ? p[2] : 0.0f;
    }
    // x(t+1) tile 32x16 (origin x0, y0) — 512 px = exactly 2 slots/thread
    float xr2[2][3];
#pragma unroll
    for (int k = 0; k < 2; ++k) {
        const int l = tid + k * 256;
        int r = l >> 5, c = l & 31;
        int gy = y0 + r, gx = x0 + c;
        const bool inb = (unsigned)gy < HH && (unsigned)gx < WW;
        const float* p = xg + (((size_t)(b * TT + t + 1) * HH + gy) * WW + gx) * CIN;
        xr2[k][0] = inb ? p[0] : 0.0f;
        xr2[k][1] = inb ? p[1] : 0.0f;
        xr2[k][2] = inb ? p[2] : 0.0f;
    }
    // h(t-1) halo 34x18
    half8 hr[3];
    if (!FIRSTPAIR) {
#pragma unroll
        for (int k = 0; k < 3; ++k) {
            const int l = tid + k * 256;
            const bool in = (l < LH * LW);
            int r = l / LW, c = l - r * LW;
            int gy = y0 - 1 + r, gx = x0 - 1 + c;
            const bool inb = in && (unsigned)gy < HH && (unsigned)gx < WW;
            half8 v = {(_Float16)0, (_Float16)0, (_Float16)0, (_Float16)0,
                       (_Float16)0, (_Float16)0, (_Float16)0, (_Float16)0};
            if (inb) v = *(const half8*)(hin + ((size_t)(b * HH + gy) * WW + gx) * FF);
            hr[k] = v;
        }
    }
    // c(t-1), per-group prefetch at this thread's own (px,ch) — coalesced u16
    half2t cpre[NG];
    if (!FIRSTPAIR) {
#pragma unroll
        for (int g = 0; g < NG; ++g) {
            const int lr  = wave * 4 + (g >> 1);
            const int gx0 = (g & 1) * 16;
            const int gy  = y0 + lr;
            const int gxa = x0 + gx0 + m0;
            const bool iny = (unsigned)gy < HH;
            half2t cv; cv.x = (_Float16)0; cv.y = (_Float16)0;
            const _Float16* cp = cin + ((size_t)(b * HH + gy) * WW + gxa) * FF + fc;
            if (iny && (unsigned)gxa < WW)       cv.x = cp[0];
            if (iny && (unsigned)(gxa + 1) < WW) cv.y = cp[FF];
            cpre[g] = cv;
        }
    }

    // ================= PHASE B: LDS writes =================
#pragma unroll
    for (int k = 0; k < 3; ++k) {
        if (xin1[k]) {
            half4 vh;
            vh.x = (_Float16)xr1[k][0];
            vh.y = (_Float16)xr1[k][1];
            vh.z = (_Float16)xr1[k][2];
            vh.w = (_Float16)0;
            xls1[tid + k * 256] = vh;
        }
    }
#pragma unroll
    for (int k = 0; k < 2; ++k) {
        half4 vh;
        vh.x = (_Float16)xr2[k][0];
        vh.y = (_Float16)xr2[k][1];
        vh.z = (_Float16)xr2[k][2];
        vh.w = (_Float16)0;
        xls2[tid + k * 256] = vh;
    }
    if (!FIRSTPAIR) {
#pragma unroll
        for (int k = 0; k < 3; ++k)
            if (xin1[k]) hls1[tid + k * 256] = hr[k];
    }
    __syncthreads();

    // ================= PHASE C: step t on full 32x16 =================
    half2t creg[NG];   // c(t) for this thread's pixels, fp16 (same rounding as r9)
#pragma unroll
    for (int g = 0; g < NG; ++g) {
        const int lr  = wave * 4 + (g >> 1);
        const int gx0 = (g & 1) * 16;
        const int lc  = gx0 + nlo;

        const int t0 = 2 * quad, t1 = t0 + 1;
        half4 p  = xls1[(lr + t0 / 3) * LW + lc + t0 % 3];
        half4 q  = xls1[(lr + t1 / 3) * LW + lc + t1 % 3];
        half4 s8 = xls1[(lr + 2) * LW + lc + 2];            // tap 8
        half8 a_xA = (half8){p.x, p.y, p.z, p.w, q.x, q.y, q.z, q.w};
        half8 a_xB = (half8){s8.x, s8.y, s8.z, s8.w, s8.x, s8.y, s8.z, s8.w};

        floatx4 acc0 = {bv0, bv0, bv0, bv0};
        floatx4 acc1 = {bv1, bv1, bv1, bv1};
        acc0 = MFMA(a_xA, bfh[0], acc0);  acc1 = MFMA(a_xA, bfh[1], acc1);
        acc0 = MFMA(a_xB, bfh[2], acc0);  acc1 = MFMA(a_xB, bfh[3], acc1);
        if (!FIRSTPAIR) {
#pragma unroll
            for (int c = 0; c < 3; ++c) {
                int tap = c * 4 + quad;
                if (tap > 8) tap = 8;          // padded taps: B rows zero
                half8 ah = hls1[(lr + tap / 3) * LW + lc + tap % 3];
                acc0 = MFMA(ah, bfh[4 + c * 2], acc0);
                acc1 = MFMA(ah, bfh[5 + c * 2], acc1);
                acc0 = MFMA(ah, bfl[c * 2 + 0], acc0);
                acc1 = MFMA(ah, bfl[c * 2 + 1], acc1);
            }
        }

        const float c0 = FIRSTPAIR ? 0.0f : (float)cpre[g].x;
        const float c1 = FIRSTPAIR ? 0.0f : (float)cpre[g].y;
        GATES(acc0, acc1, c0, c1, cn0, cn1, hn0, hn1);

        half2t cc; cc.x = (_Float16)cn0; cc.y = (_Float16)cn1;
        creg[g] = cc;

        // h(t) -> LDS, zero-masked outside the image (= 'SAME' zero padding)
        const int gy   = y0 + lr;
        const int colm = gx0 + m0;
        const int gxa  = x0 + colm;
        const bool iny = (unsigned)gy < HH;
        _Float16 h0v = (_Float16)hn0, h1v = (_Float16)hn1;
        if (!(iny && (unsigned)gxa < WW))       h0v = (_Float16)0;
        if (!(iny && (unsigned)(gxa + 1) < WW)) h1v = (_Float16)0;
        hls2[(lr * TW + colm) * FF + fc]     = h0v;
        hls2[(lr * TW + colm + 1) * FF + fc] = h1v;
    }
    __syncthreads();

    // ================= PHASE D: step t+1, interior 30x14 =================
#pragma unroll
    for (int g = 0; g < NG; ++g) {
        const int lr  = wave * 4 + (g >> 1);
        const int gx0 = (g & 1) * 16;
        const int lc  = gx0 + nlo;

        // x(t+1) taps from xls2 (origin (0,0), no halo) — clamped reads;
        // border outputs are masked so clamped garbage is harmless, and
        // out-of-image staged values are already 0 (correct padding).
        const int t0 = 2 * quad, t1 = t0 + 1;
        half4 p  = xls2[clampi(lr + t0 / 3 - 1, 0, THT - 1) * TW + clampi(lc + t0 % 3 - 1, 0, TW - 1)];
        half4 q  = xls2[clampi(lr + t1 / 3 - 1, 0, THT - 1) * TW + clampi(lc + t1 % 3 - 1, 0, TW - 1)];
        half4 s8 = xls2[clampi(lr + 1, 0, THT - 1) * TW + clampi(lc + 1, 0, TW - 1)]; // tap 8
        half8 a_xA = (half8){p.x, p.y, p.z, p.w, q.x, q.y, q.z, q.w};
        half8 a_xB = (half8){s8.x, s8.y, s8.z, s8.w, s8.x, s8.y, s8.z, s8.w};

        floatx4 acc0 = {bv0, bv0, bv0, bv0};
        floatx4 acc1 = {bv1, bv1, bv1, bv1};
        acc0 = MFMA(a_xA, bfh[0], acc0);  acc1 = MFMA(a_xA, bfh[1], acc1);
        acc0 = MFMA(a_xB, bfh[2], acc0);  acc1 = MFMA(a_xB, bfh[3], acc1);
#pragma unroll
        for (int c = 0; c < 3; ++c) {
            int tap = c * 4 + quad;
            if (tap > 8) tap = 8;
            const int rr = clampi(lr + tap / 3 - 1, 0, THT - 1);
            const int cc = clampi(lc + tap % 3 - 1, 0, TW - 1);
            half8 ah = *(const half8*)(hls2 + (rr * TW + cc) * FF);
            acc0 = MFMA(ah, bfh[4 + c * 2], acc0);
            acc1 = MFMA(ah, bfh[5 + c * 2], acc1);
            acc0 = MFMA(ah, bfl[c * 2 + 0], acc0);
            acc1 = MFMA(ah, bfl[c * 2 + 1], acc1);
        }

        GATES(acc0, acc1, (float)creg[g].x, (float)creg[g].y, cn0, cn1, hn0, hn1);

        // interior-masked plain-layout writes
        const int gy   = y0 + lr;
        const int colm = gx0 + m0;
        const int gxa  = x0 + colm;
        const bool rowok = (lr >= 1) && (lr <= SH) && ((unsigned)gy < HH);
        const bool c0ok = rowok && (colm >= 1) && (colm <= SW) && ((unsigned)gxa < WW);
        const bool c1ok = rowok && (colm + 1 <= SW) && ((unsigned)(gxa + 1) < WW);
        const size_t base = ((size_t)(b * HH + gy) * WW + gxa) * FF + fc;
        if (c0ok) {
            hout[base] = (_Float16)hn0;
            cout[base] = (_Float16)cn0;
        }
        if (c1ok) {
            hout[base + FF] = (_Float16)hn1;
            cout[base + FF] = (_Float16)cn1;
        }
    }
}

// ---------------------------------------------------------------------------
// Last step (t=4) + fused epilogue. Non-overlapping 32x16 tiles as in r9.
// Reads h(3) (halo) and c(3) (plain layout, always in-image).
// ---------------------------------------------------------------------------
__global__ __launch_bounds__(256) void lstm_last(
    const float* __restrict__ xg,
    const _Float16* __restrict__ blob,
    const float* __restrict__ bias,
    const _Float16* __restrict__ hin,   // h(3)
    const _Float16* __restrict__ cin,   // c(3) plain
    const float* __restrict__ gamma, const float* __restrict__ beta,
    const float* __restrict__ mean,  const float* __restrict__ var,
    const float* __restrict__ dw,    const float* __restrict__ db,
    float* __restrict__ out)            // [B,H,W,2]
{
    __shared__ half8 hls[LH * LW];
    __shared__ half4 xls[LH * LW];

    const int tid  = threadIdx.x;
    const int lane = tid & 63, wave = tid >> 6;
    const int quad = lane >> 4, nlo = lane & 15;
    const bool lo8 = (nlo < 8);
    const int fc = nlo & 7;
    const int m0 = quad * 4 + (lo8 ? 0 : 2);
    const int bx = blockIdx.x, by = blockIdx.y, b = blockIdx.z;
    const int t = TT - 1;

    half8 bfh[10], bfl[6];
#pragma unroll
    for (int i = 0; i < 10; ++i)
        bfh[i] = *(const half8*)(blob + ((size_t)i * 64 + lane) * 8);
#pragma unroll
    for (int i = 0; i < 6; ++i)
        bfl[i] = *(const half8*)(blob + ((size_t)(10 + i) * 64 + lane) * 8);

    const float bv0 = bias[nlo] * (-LOG2E);
    const float bv1 = bias[16 + nlo] * (lo8 ? 2.0f * LOG2E : -LOG2E);

    // ---- PHASE A ----
    float xr[3][3];
    bool  xin[3];
#pragma unroll
    for (int k = 0; k < 3; ++k) {
        const int l = tid + k * 256;
        const bool in = (l < LH * LW);
        xin[k] = in;
        int r = l / LW, c = l - r * LW;
        int gy = by * THT + r - 1, gx = bx * TW + c - 1;
        const bool inb = in && (unsigned)gy < HH && (unsigned)gx < WW;
        const float* p = xg + (((size_t)(b * TT + t) * HH + gy) * WW + gx) * CIN;
        xr[k][0] = inb ? p[0] : 0.0f;
        xr[k][1] = inb ? p[1] : 0.0f;
        xr[k][2] = inb ? p[2] : 0.0f;
    }
    half8 hr[3];
#pragma unroll
    for (int k = 0; k < 3; ++k) {
        const int l = tid + k * 256;
        const bool in = (l < LH * LW);
        int r = l / LW, c = l - r * LW;
        int gy = by * THT + r - 1, gx = bx * TW + c - 1;
        const bool inb = in && (unsigned)gy < HH && (unsigned)gx < WW;
        half8 v = {(_Float16)0, (_Float16)0, (_Float16)0, (_Float16)0,
                   (_Float16)0, (_Float16)0, (_Float16)0, (_Float16)0};
        if (inb) v = *(const half8*)(hin + ((size_t)(b * HH + gy) * WW + gx) * FF);
        hr[k] = v;
    }
    half2t cpre[NG];
#pragma unroll
    for (int g = 0; g < NG; ++g) {
        const int lr  = wave * 4 + (g >> 1);
        const int gx0 = (g & 1) * 16;
        const int gy  = by * THT + lr;
        const int gxa = bx * TW + gx0 + m0;
        const _Float16* cp = cin + ((size_t)(b * HH + gy) * WW + gxa) * FF + fc;
        half2t cv; cv.x = cp[0]; cv.y = cp[FF];
        cpre[g] = cv;
    }

    // ---- PHASE B ----
#pragma unroll
    for (int k = 0; k < 3; ++k) {
        if (xin[k]) {
            half4 vh;
            vh.x = (_Float16)xr[k][0];
            vh.y = (_Float16)xr[k][1];
            vh.z = (_Float16)xr[k][2];
            vh.w = (_Float16)0;
            xls[tid + k * 256] = vh;
            hls[tid + k * 256] = hr[k];
        }
    }
    __syncthreads();

    // epilogue constants
    const float bn_s = gamma[fc] * rsqrtf(var[fc] + 1e-3f);
    const float bn_b = beta[fc] - mean[fc] * bn_s;
    const float dw0 = dw[fc * 2 + 0], dw1 = dw[fc * 2 + 1];
    const float db0 = db[0], db1 = db[1];

#pragma unroll
    for (int g = 0; g < NG; ++g) {
        const int lr  = wave * 4 + (g >> 1);
        const int gx0 = (g & 1) * 16;
        const int lc  = gx0 + nlo;

        const int t0 = 2 * quad, t1 = t0 + 1;
        half4 p  = xls[(lr + t0 / 3) * LW + lc + t0 % 3];
        half4 q  = xls[(lr + t1 / 3) * LW + lc + t1 % 3];
        half4 s8 = xls[(lr + 2) * LW + lc + 2];
        half8 a_xA = (half8){p.x, p.y, p.z, p.w, q.x, q.y, q.z, q.w};
        half8 a_xB = (half8){s8.x, s8.y, s8.z, s8.w, s8.x, s8.y, s8.z, s8.w};

        floatx4 acc0 = {bv0, bv0, bv0, bv0};
        floatx4 acc1 = {bv1, bv1, bv1, bv1};
        acc0 = MFMA(a_xA, bfh[0], acc0);  acc1 = MFMA(a_xA, bfh[1], acc1);
        acc0 = MFMA(a_xB, bfh[2], acc0);  acc1 = MFMA(a_xB, bfh[3], acc1);
#pragma unroll
        for (int c = 0; c < 3; ++c) {
            int tap = c * 4 + quad;
            if (tap > 8) tap = 8;
            half8 ah = hls[(lr + tap / 3) * LW + lc + tap % 3];
            acc0 = MFMA(ah, bfh[4 + c * 2], acc0);
            acc1 = MFMA(ah, bfh[5 + c * 2], acc1);
            acc0 = MFMA(ah, bfl[c * 2 + 0], acc0);
            acc1 = MFMA(ah, bfl[c * 2 + 1], acc1);
        }

        GATES(acc0, acc1, (float)cpre[g].x, (float)cpre[g].y, cn0, cn1, hn0, hn1);
        (void)cn0; (void)cn1;

        // ---- fused epilogue: BN -> LeakyReLU(0.3) -> Dense(8->2) ----
        const int gy = by * THT + lr;
        float y0 = bn_s * hn0 + bn_b; y0 = (y0 >= 0.f) ? y0 : 0.3f * y0;
        float y1 = bn_s * hn1 + bn_b; y1 = (y1 >= 0.f) ? y1 : 0.3f * y1;
        float p00 = y0 * dw0, p01 = y0 * dw1;
        float p10 = y1 * dw0, p11 = y1 * dw1;
#pragma unroll
        for (int m = 1; m <= 4; m <<= 1) {
            p00 += __shfl_xor(p00, m, 64);
            p01 += __shfl_xor(p01, m, 64);
            p10 += __shfl_xor(p10, m, 64);
            p11 += __shfl_xor(p11, m, 64);
        }
        const int j = nlo & 7;
        if (j < 4) {
            const int px = m0 + (j >> 1);
            const int k  = j & 1;
            float val = (j == 0 ? p00 : j == 1 ? p01 : j == 2 ? p10 : p11)
                        + (k ? db1 : db0);
            out[((size_t)(b * HH + gy) * WW + bx * TW + gx0 + px) * 2 + k] = val;
        }
    }
}

extern "C" void kernel_launch(void* const* d_in, const int* in_sizes, int n_in,
                              void* d_out, int out_size, void* d_ws, size_t ws_size,
                              hipStream_t stream) {
    const float* x     = (const float*)d_in[0];
    const float* wk    = (const float*)d_in[1];
    const float* wr    = (const float*)d_in[2];
    const float* bias  = (const float*)d_in[3];
    const float* gamma = (const float*)d_in[4];
    const float* beta  = (const float*)d_in[5];
    const float* mean  = (const float*)d_in[6];
    const float* var   = (const float*)d_in[7];
    const float* dw    = (const float*)d_in[8];
    const float* db    = (const float*)d_in[9];
    float* out = (float*)d_out;

    // ws: blob 32KB | hA | hB | cA | cB (each 16.78MB fp16) = 67.2MB total
    const size_t state = (size_t)BB * HH * WW * FF;
    _Float16* blob = (_Float16*)d_ws;
    _Float16* hA = (_Float16*)((char*)d_ws + 32768);
    _Float16* hB = hA + state;
    _Float16* cA = hB + state;
    _Float16* cB = cA + state;

    build_frags<<<1, 64, 0, stream>>>(wk, wr, blob);

    dim3 pgrid(NPX, NPY, BB), block(256);
    // pair (0,1): no h/c input; writes h(1)->hA, c(1)->cA
    lstm_pair<1><<<pgrid, block, 0, stream>>>(x, 0, blob, bias,
                                              nullptr, hA, nullptr, cA);
    // pair (2,3): reads hA/cA; writes h(3)->hB, c(3)->cB
    lstm_pair<0><<<pgrid, block, 0, stream>>>(x, 2, blob, bias,
                                              hA, hB, cA, cB);
    // step 4 + epilogue
    dim3 lgrid(WW / TW, HH / THT, BB);
    lstm_last<<<lgrid, block, 0, stream>>>(x, blob, bias, hB, cB,
                                           gamma, beta, mean, var, dw, db, out);
}

// Round 8
// 287.714 us; speedup vs baseline: 3.3034x; 1.0162x over previous
//
#include <hip/hip_runtime.h>

// ConvLSTM2D (B=16,T=5,H=W=256,Cin=3,F=8) + BN + LeakyReLU + Dense(8->2)
// Round-17: WAVE-PRIVATE TILES, ZERO BARRIERS. r16 pair fusion passed @292us
// but per-dispatch counters (hbm 0.8TB/s, Mfma 18%, VALU 40%, occ 19%) show
// ~2 block-pipelines/CU in lockstep: barriers + one long chain per block.
// Now: block = 64 thr = ONE wave owning a private 16x16 tile (interior 14x14,
// same 2-step fusion). All LDS deps are same-wave (lockstep, in-order LDS
// pipe) -> no __syncthreads at all. 13.9KB LDS/block -> 11 independent
// pipelines/CU. x2 loads issued after phase C starts (hide under compute).
// Numerics identical to r16 (same staging, fp16 rounding, GATES).
// grid pair: 19x19x16 (stride 14); last: 16x16x16. Launches unchanged (4).

#define BB  16
#define TT  5
#define HH  256
#define WW  256
#define CIN 3
#define FF  8
#define GG  32

#define TIW 16   // computed tile (16x16)
#define TLW 18   // staged halo width (16+2)
#define STR 14   // pair interior stride
#define NPT 19   // ceil(256/14)

#define LOG2E 1.44269504088896340736f

typedef _Float16 half8  __attribute__((ext_vector_type(8)));
typedef _Float16 half4  __attribute__((ext_vector_type(4)));
typedef _Float16 half2t __attribute__((ext_vector_type(2)));
typedef float    floatx4 __attribute__((ext_vector_type(4)));

__device__ __forceinline__ float frcp(float x) { return __builtin_amdgcn_rcpf(x); }
// z pre-scaled by -log2e:  sigmoid(z0) = 1/(1+2^z)
__device__ __forceinline__ float sig2(float z)  { return frcp(1.0f + __builtin_amdgcn_exp2f(z)); }
// z pre-scaled by +2log2e: tanh(z0) = 1 - 2/(1+2^z)
__device__ __forceinline__ float tanh2(float z) { return 1.0f - 2.0f * frcp(1.0f + __builtin_amdgcn_exp2f(z)); }

__device__ __forceinline__ int clampi(int v, int lo, int hi) {
    return v < lo ? lo : (v > hi ? hi : v);
}

#define MFMA(A, B, C) __builtin_amdgcn_mfma_f32_16x16x32_f16((A), (B), (C), 0, 0, 0)

// Gate phase (verbatim r9/r16 logic).
#define GATES(ACC0, ACC1, C0, C1, CN0, CN1, HN0, HN1)                         \
  float CN0, CN1, HN0, HN1;                                                   \
  {                                                                           \
    float s0 = lo8 ? ACC0[2] : ACC0[0]; float r0 = __shfl_xor(s0, 8, 64);     \
    float s1 = lo8 ? ACC0[3] : ACC0[1]; float r1 = __shfl_xor(s1, 8, 64);     \
    float s2 = lo8 ? ACC1[2] : ACC1[0]; float r2 = __shfl_xor(s2, 8, 64);     \
    float s3 = lo8 ? ACC1[3] : ACC1[1]; float r3 = __shfl_xor(s3, 8, 64);     \
    const float zi0 = lo8 ? ACC0[0] : r0, zi1 = lo8 ? ACC0[1] : r1;           \
    const float zf0 = lo8 ? r0 : ACC0[2], zf1 = lo8 ? r1 : ACC0[3];           \
    const float zg0 = lo8 ? ACC1[0] : r2, zg1 = lo8 ? ACC1[1] : r3;           \
    const float zo0 = lo8 ? r2 : ACC1[2], zo1 = lo8 ? r3 : ACC1[3];           \
    const float ii0 = sig2(zi0), ff0 = sig2(zf0), gg0 = tanh2(zg0), oo0 = sig2(zo0); \
    CN0 = ff0 * (C0) + ii0 * gg0;                                             \
    HN0 = oo0 * tanh2(CN0 * (2.0f * LOG2E));                                  \
    const float ii1 = sig2(zi1), ff1 = sig2(zf1), gg1 = tanh2(zg1), oo1 = sig2(zo1); \
    CN1 = ff1 * (C1) + ii1 * gg1;                                             \
    HN1 = oo1 * tanh2(CN1 * (2.0f * LOG2E));                                  \
  }

// ---------------------------------------------------------------------------
// Setup: 16 B-fragments (unchanged from r16; see notes there).
// ---------------------------------------------------------------------------
__global__ void build_frags(const float* __restrict__ wk,
                            const float* __restrict__ wr,
                            _Float16* __restrict__ blob) {
    const int lane = threadIdx.x & 63;
    const int quad = lane >> 4, nlo = lane & 15;
    for (int chunk = 0; chunk < 5; ++chunk) {
        for (int nh = 0; nh < 2; ++nh) {
            const int n = nh * 16 + nlo;
            const float scale = (n >= 16 && n < 24) ? (2.0f * LOG2E) : (-LOG2E);
            const int frag = chunk * 2 + nh;
            _Float16* dhi = blob + ((size_t)frag * 64 + lane) * 8;
            _Float16* dlo = (chunk >= 2)
                ? blob + ((size_t)(10 + (chunk - 2) * 2 + nh) * 64 + lane) * 8
                : nullptr;
            for (int j = 0; j < 8; ++j) {
                const int k = quad * 8 + j;
                float w = 0.0f;
                if (chunk == 0) {
                    int tap = k >> 2, ci = k & 3;
                    if (ci < 3) w = wk[(tap * 3 + ci) * GG + n];
                } else if (chunk == 1) {
                    if (quad == 0 && j < 3) w = wk[(8 * 3 + j) * GG + n];
                } else {
                    int c = chunk - 2;
                    int tap = c * 4 + quad, ci = j;
                    if (tap < 9) w = wr[(tap * FF + ci) * GG + n];
                }
                w *= scale;
                _Float16 wh = (_Float16)w;
                dhi[j] = wh;
                if (dlo) dlo[j] = (_Float16)(w - (float)wh);
            }
        }
    }
}

// ---------------------------------------------------------------------------
// Pair kernel, wave-private: one 64-thread block = one wave = one 16x16 tile.
// Steps t (full 16x16) and t+1 (interior 14x14 written). No barriers.
// ---------------------------------------------------------------------------
template <int FIRSTPAIR>
__global__ __launch_bounds__(64) void lstm_pair(
    const float* __restrict__ xg,       // [B,T,H,W,3] fp32
    int t,
    const _Float16* __restrict__ blob,
    const float* __restrict__ bias,
    const _Float16* __restrict__ hin,   // h(t-1) plain [b,y,x,8]
    _Float16* __restrict__ hout,        // h(t+1) plain
    const _Float16* __restrict__ cin,   // c(t-1) plain
    _Float16* __restrict__ cout)        // c(t+1) plain
{
    __shared__ half4 xls1[TLW * TLW];                      // x(t) halo  (2592 B)
    __shared__ half8 hls1[TLW * TLW];                      // h(t-1) halo (5184 B)
    __shared__ half4 xls2[TIW * TIW];                      // x(t+1)     (2048 B)
    __shared__ __align__(16) _Float16 hls2[TIW * TIW * FF];// h(t)       (4096 B)

    const int lane = threadIdx.x;        // 0..63, one wave
    const int quad = lane >> 4, nlo = lane & 15;
    const bool lo8 = (nlo < 8);
    const int fc = nlo & 7;
    const int m0 = quad * 4 + (lo8 ? 0 : 2);

    const int bx = blockIdx.x, by = blockIdx.y, b = blockIdx.z;
    const int x0 = bx * STR - 1, y0 = by * STR - 1;  // computed-tile origin

    // B-fragments (L2-hot)
    half8 bfh[10], bfl[6];
#pragma unroll
    for (int i = 0; i < 10; ++i)
        bfh[i] = *(const half8*)(blob + ((size_t)i * 64 + lane) * 8);
#pragma unroll
    for (int i = 0; i < 6; ++i)
        bfl[i] = *(const half8*)(blob + ((size_t)(10 + i) * 64 + lane) * 8);

    const float bv0 = bias[nlo] * (-LOG2E);
    const float bv1 = bias[16 + nlo] * (lo8 ? 2.0f * LOG2E : -LOG2E);

    // ===== PHASE A: issue x(t) halo, h halo, c loads =====
    float xr1[6][3];
#pragma unroll
    for (int k = 0; k < 6; ++k) {
        const int l = lane + k * 64;
        const bool in = (l < TLW * TLW);
        const int r = l / TLW, c = l - r * TLW;
        const int gy = y0 - 1 + r, gx = x0 - 1 + c;
        const bool inb = in && (unsigned)gy < HH && (unsigned)gx < WW;
        const float* p = xg + (((size_t)(b * TT + t) * HH + gy) * WW + gx) * CIN;
        xr1[k][0] = inb ? p[0] : 0.0f;
        xr1[k][1] = inb ? p[1] : 0.0f;
        xr1[k][2] = inb ? p[2] : 0.0f;
    }
    half8 hr[6];
    if (!FIRSTPAIR) {
#pragma unroll
        for (int k = 0; k < 6; ++k) {
            const int l = lane + k * 64;
            const bool in = (l < TLW * TLW);
            const int r = l / TLW, c = l - r * TLW;
            const int gy = y0 - 1 + r, gx = x0 - 1 + c;
            const bool inb = in && (unsigned)gy < HH && (unsigned)gx < WW;
            half8 v = {(_Float16)0, (_Float16)0, (_Float16)0, (_Float16)0,
                       (_Float16)0, (_Float16)0, (_Float16)0, (_Float16)0};
            if (inb) v = *(const half8*)(hin + ((size_t)(b * HH + gy) * WW + gx) * FF);
            hr[k] = v;
        }
    }
    half2t creg[TIW];
#pragma unroll
    for (int g = 0; g < TIW; ++g) {
        half2t cv; cv.x = (_Float16)0; cv.y = (_Float16)0;
        if (!FIRSTPAIR) {
            const int gy = y0 + g, gxa = x0 + m0;
            const bool iny = (unsigned)gy < HH;
            const _Float16* cp = cin + ((size_t)(b * HH + gy) * WW + gxa) * FF + fc;
            if (iny && (unsigned)gxa < WW)       cv.x = cp[0];
            if (iny && (unsigned)(gxa + 1) < WW) cv.y = cp[FF];
        }
        creg[g] = cv;
    }

    // ===== PHASE B: stage x1 + h1 (same-wave LDS, no barrier needed) =====
#pragma unroll
    for (int k = 0; k < 6; ++k) {
        const int l = lane + k * 64;
        if (l < TLW * TLW) {
            half4 vh;
            vh.x = (_Float16)xr1[k][0];
            vh.y = (_Float16)xr1[k][1];
            vh.z = (_Float16)xr1[k][2];
            vh.w = (_Float16)0;
            xls1[l] = vh;
            if (!FIRSTPAIR) hls1[l] = hr[k];
        }
    }

    // issue x(t+1) loads now: in flight during phase C
    float xr2[4][3];
#pragma unroll
    for (int k = 0; k < 4; ++k) {
        const int l = lane + k * 64;
        const int r = l >> 4, c = l & 15;
        const int gy = y0 + r, gx = x0 + c;
        const bool inb = (unsigned)gy < HH && (unsigned)gx < WW;
        const float* p = xg + (((size_t)(b * TT + t + 1) * HH + gy) * WW + gx) * CIN;
        xr2[k][0] = inb ? p[0] : 0.0f;
        xr2[k][1] = inb ? p[1] : 0.0f;
        xr2[k][2] = inb ? p[2] : 0.0f;
    }

    // ===== PHASE C: step t on full 16x16 (one row per group) =====
#pragma unroll
    for (int g = 0; g < TIW; ++g) {
        const int t0 = 2 * quad, t1 = t0 + 1;
        half4 p  = xls1[(g + t0 / 3) * TLW + nlo + t0 % 3];
        half4 q  = xls1[(g + t1 / 3) * TLW + nlo + t1 % 3];
        half4 s8 = xls1[(g + 2) * TLW + nlo + 2];            // tap 8
        half8 a_xA = (half8){p.x, p.y, p.z, p.w, q.x, q.y, q.z, q.w};
        half8 a_xB = (half8){s8.x, s8.y, s8.z, s8.w, s8.x, s8.y, s8.z, s8.w};

        floatx4 acc0 = {bv0, bv0, bv0, bv0};
        floatx4 acc1 = {bv1, bv1, bv1, bv1};
        acc0 = MFMA(a_xA, bfh[0], acc0);  acc1 = MFMA(a_xA, bfh[1], acc1);
        acc0 = MFMA(a_xB, bfh[2], acc0);  acc1 = MFMA(a_xB, bfh[3], acc1);
        if (!FIRSTPAIR) {
#pragma unroll
            for (int c = 0; c < 3; ++c) {
                int tap = c * 4 + quad;
                if (tap > 8) tap = 8;          // padded taps: B rows zero
                half8 ah = hls1[(g + tap / 3) * TLW + nlo + tap % 3];
                acc0 = MFMA(ah, bfh[4 + c * 2], acc0);
                acc1 = MFMA(ah, bfh[5 + c * 2], acc1);
                acc0 = MFMA(ah, bfl[c * 2 + 0], acc0);
                acc1 = MFMA(ah, bfl[c * 2 + 1], acc1);
            }
        }

        GATES(acc0, acc1, (float)creg[g].x, (float)creg[g].y, cn0, cn1, hn0, hn1);

        half2t cc; cc.x = (_Float16)cn0; cc.y = (_Float16)cn1;
        creg[g] = cc;

        // h(t) -> LDS, zero-masked outside the image ('SAME' padding)
        const int gy  = y0 + g;
        const int gxa = x0 + m0;
        const bool iny = (unsigned)gy < HH;
        _Float16 h0v = (_Float16)hn0, h1v = (_Float16)hn1;
        if (!(iny && (unsigned)gxa < WW))       h0v = (_Float16)0;
        if (!(iny && (unsigned)(gxa + 1) < WW)) h1v = (_Float16)0;
        hls2[(g * TIW + m0) * FF + fc]     = h0v;
        hls2[(g * TIW + m0 + 1) * FF + fc] = h1v;
    }

    // stage x(t+1) (loads have been in flight during phase C)
#pragma unroll
    for (int k = 0; k < 4; ++k) {
        const int l = lane + k * 64;
        half4 vh;
        vh.x = (_Float16)xr2[k][0];
        vh.y = (_Float16)xr2[k][1];
        vh.z = (_Float16)xr2[k][2];
        vh.w = (_Float16)0;
        xls2[l] = vh;
    }

    // ===== PHASE D: step t+1, interior 14x14 written =====
#pragma unroll
    for (int g = 0; g < TIW; ++g) {
        const int t0 = 2 * quad, t1 = t0 + 1;
        half4 p  = xls2[clampi(g + t0 / 3 - 1, 0, TIW - 1) * TIW + clampi(nlo + t0 % 3 - 1, 0, TIW - 1)];
        half4 q  = xls2[clampi(g + t1 / 3 - 1, 0, TIW - 1) * TIW + clampi(nlo + t1 % 3 - 1, 0, TIW - 1)];
        half4 s8 = xls2[clampi(g + 1, 0, TIW - 1) * TIW + clampi(nlo + 1, 0, TIW - 1)];
        half8 a_xA = (half8){p.x, p.y, p.z, p.w, q.x, q.y, q.z, q.w};
        half8 a_xB = (half8){s8.x, s8.y, s8.z, s8.w, s8.x, s8.y, s8.z, s8.w};

        floatx4 acc0 = {bv0, bv0, bv0, bv0};
        floatx4 acc1 = {bv1, bv1, bv1, bv1};
        acc0 = MFMA(a_xA, bfh[0], acc0);  acc1 = MFMA(a_xA, bfh[1], acc1);
        acc0 = MFMA(a_xB, bfh[2], acc0);  acc1 = MFMA(a_xB, bfh[3], acc1);
#pragma unroll
        for (int c = 0; c < 3; ++c) {
            int tap = c * 4 + quad;
            if (tap > 8) tap = 8;
            const int rr = clampi(g + tap / 3 - 1, 0, TIW - 1);
            const int cc = clampi(nlo + tap % 3 - 1, 0, TIW - 1);
            half8 ah = *(const half8*)(hls2 + (rr * TIW + cc) * FF);
            acc0 = MFMA(ah, bfh[4 + c * 2], acc0);
            acc1 = MFMA(ah, bfh[5 + c * 2], acc1);
            acc0 = MFMA(ah, bfl[c * 2 + 0], acc0);
            acc1 = MFMA(ah, bfl[c * 2 + 1], acc1);
        }

        GATES(acc0, acc1, (float)creg[g].x, (float)creg[g].y, cn0, cn1, hn0, hn1);

        // interior-masked plain-layout writes (local rows/cols 1..14)
        const int gy  = y0 + g;
        const int gxa = x0 + m0;
        const bool rowok = (g >= 1) && (g <= STR) && ((unsigned)gy < HH);
        const bool c0ok = rowok && (m0 >= 1) && (m0 <= STR) && ((unsigned)gxa < WW);
        const bool c1ok = rowok && (m0 + 1 <= STR) && ((unsigned)(gxa + 1) < WW);
        const size_t base = ((size_t)(b * HH + gy) * WW + gxa) * FF + fc;
        if (c0ok) {
            hout[base] = (_Float16)cn0, hout[base] = (_Float16)hn0;
            cout[base] = (_Float16)cn0;
        }
        if (c1ok) {
            hout[base + FF] = (_Float16)hn1;
            cout[base + FF] = (_Float16)cn1;
        }
    }
}

// ---------------------------------------------------------------------------
// Last step (t=4) + fused epilogue, wave-private 16x16 non-overlap tiles.
// ---------------------------------------------------------------------------
__global__ __launch_bounds__(64) void lstm_last(
    const float* __restrict__ xg,
    const _Float16* __restrict__ blob,
    const float* __restrict__ bias,
    const _Float16* __restrict__ hin,   // h(3)
    const _Float16* __restrict__ cin,   // c(3) plain
    const float* __restrict__ gamma, const float* __restrict__ beta,
    const float* __restrict__ mean,  const float* __restrict__ var,
    const float* __restrict__ dw,    const float* __restrict__ db,
    float* __restrict__ out)            // [B,H,W,2]
{
    __shared__ half4 xls1[TLW * TLW];
    __shared__ half8 hls1[TLW * TLW];

    const int lane = threadIdx.x;
    const int quad = lane >> 4, nlo = lane & 15;
    const bool lo8 = (nlo < 8);
    const int fc = nlo & 7;
    const int m0 = quad * 4 + (lo8 ? 0 : 2);
    const int bx = blockIdx.x, by = blockIdx.y, b = blockIdx.z;
    const int x0 = bx * TIW, y0 = by * TIW;
    const int t = TT - 1;

    half8 bfh[10], bfl[6];
#pragma unroll
    for (int i = 0; i < 10; ++i)
        bfh[i] = *(const half8*)(blob + ((size_t)i * 64 + lane) * 8);
#pragma unroll
    for (int i = 0; i < 6; ++i)
        bfl[i] = *(const half8*)(blob + ((size_t)(10 + i) * 64 + lane) * 8);

    const float bv0 = bias[nlo] * (-LOG2E);
    const float bv1 = bias[16 + nlo] * (lo8 ? 2.0f * LOG2E : -LOG2E);

    // ---- loads ----
    float xr1[6][3];
    half8 hr[6];
#pragma unroll
    for (int k = 0; k < 6; ++k) {
        const int l = lane + k * 64;
        const bool in = (l < TLW * TLW);
        const int r = l / TLW, c = l - r * TLW;
        const int gy = y0 - 1 + r, gx = x0 - 1 + c;
        const bool inb = in && (unsigned)gy < HH && (unsigned)gx < WW;
        const float* p = xg + (((size_t)(b * TT + t) * HH + gy) * WW + gx) * CIN;
        xr1[k][0] = inb ? p[0] : 0.0f;
        xr1[k][1] = inb ? p[1] : 0.0f;
        xr1[k][2] = inb ? p[2] : 0.0f;
        half8 v = {(_Float16)0, (_Float16)0, (_Float16)0, (_Float16)0,
                   (_Float16)0, (_Float16)0, (_Float16)0, (_Float16)0};
        if (inb) v = *(const half8*)(hin + ((size_t)(b * HH + gy) * WW + gx) * FF);
        hr[k] = v;
    }
    half2t creg[TIW];
#pragma unroll
    for (int g = 0; g < TIW; ++g) {
        const int gy = y0 + g, gxa = x0 + m0;
        const _Float16* cp = cin + ((size_t)(b * HH + gy) * WW + gxa) * FF + fc;
        half2t cv; cv.x = cp[0]; cv.y = cp[FF];
        creg[g] = cv;
    }

    // ---- stage ----
#pragma unroll
    for (int k = 0; k < 6; ++k) {
        const int l = lane + k * 64;
        if (l < TLW * TLW) {
            half4 vh;
            vh.x = (_Float16)xr1[k][0];
            vh.y = (_Float16)xr1[k][1];
            vh.z = (_Float16)xr1[k][2];
            vh.w = (_Float16)0;
            xls1[l] = vh;
            hls1[l] = hr[k];
        }
    }

    // epilogue constants
    const float bn_s = gamma[fc] * rsqrtf(var[fc] + 1e-3f);
    const float bn_b = beta[fc] - mean[fc] * bn_s;
    const float dw0 = dw[fc * 2 + 0], dw1 = dw[fc * 2 + 1];
    const float db0 = db[0], db1 = db[1];

    // ---- compute + epilogue ----
#pragma unroll
    for (int g = 0; g < TIW; ++g) {
        const int t0 = 2 * quad, t1 = t0 + 1;
        half4 p  = xls1[(g + t0 / 3) * TLW + nlo + t0 % 3];
        half4 q  = xls1[(g + t1 / 3) * TLW + nlo + t1 % 3];
        half4 s8 = xls1[(g + 2) * TLW + nlo + 2];
        half8 a_xA = (half8){p.x, p.y, p.z, p.w, q.x, q.y, q.z, q.w};
        half8 a_xB = (half8){s8.x, s8.y, s8.z, s8.w, s8.x, s8.y, s8.z, s8.w};

        floatx4 acc0 = {bv0, bv0, bv0, bv0};
        floatx4 acc1 = {bv1, bv1, bv1, bv1};
        acc0 = MFMA(a_xA, bfh[0], acc0);  acc1 = MFMA(a_xA, bfh[1], acc1);
        acc0 = MFMA(a_xB, bfh[2], acc0);  acc1 = MFMA(a_xB, bfh[3], acc1);
#pragma unroll
        for (int c = 0; c < 3; ++c) {
            int tap = c * 4 + quad;
            if (tap > 8) tap = 8;
            half8 ah = hls1[(g + tap / 3) * TLW + nlo + tap % 3];
            acc0 = MFMA(ah, bfh[4 + c * 2], acc0);
            acc1 = MFMA(ah, bfh[5 + c * 2], acc1);
            acc0 = MFMA(ah, bfl[c * 2 + 0], acc0);
            acc1 = MFMA(ah, bfl[c * 2 + 1], acc1);
        }

        GATES(acc0, acc1, (float)creg[g].x, (float)creg[g].y, cn0, cn1, hn0, hn1);
        (void)cn0; (void)cn1;

        // ---- fused epilogue: BN -> LeakyReLU(0.3) -> Dense(8->2) ----
        const int gy = y0 + g;
        float y0v = bn_s * hn0 + bn_b; y0v = (y0v >= 0.f) ? y0v : 0.3f * y0v;
        float y1v = bn_s * hn1 + bn_b; y1v = (y1v >= 0.f) ? y1v : 0.3f * y1v;
        float p00 = y0v * dw0, p01 = y0v * dw1;
        float p10 = y1v * dw0, p11 = y1v * dw1;
#pragma unroll
        for (int m = 1; m <= 4; m <<= 1) {
            p00 += __shfl_xor(p00, m, 64);
            p01 += __shfl_xor(p01, m, 64);
            p10 += __shfl_xor(p10, m, 64);
            p11 += __shfl_xor(p11, m, 64);
        }
        const int j = nlo & 7;
        if (j < 4) {
            const int px = m0 + (j >> 1);
            const int k  = j & 1;
            float val = (j == 0 ? p00 : j == 1 ? p01 : j == 2 ? p10 : p11)
                        + (k ? db1 : db0);
            out[((size_t)(b * HH + gy) * WW + x0 + px) * 2 + k] = val;
        }
    }
}

extern "C" void kernel_launch(void* const* d_in, const int* in_sizes, int n_in,
                              void* d_out, int out_size, void* d_ws, size_t ws_size,
                              hipStream_t stream) {
    const float* x     = (const float*)d_in[0];
    const float* wk    = (const float*)d_in[1];
    const float* wr    = (const float*)d_in[2];
    const float* bias  = (const float*)d_in[3];
    const float* gamma = (const float*)d_in[4];
    const float* beta  = (const float*)d_in[5];
    const float* mean  = (const float*)d_in[6];
    const float* var   = (const float*)d_in[7];
    const float* dw    = (const float*)d_in[8];
    const float* db    = (const float*)d_in[9];
    float* out = (float*)d_out;

    // ws: blob 32KB | hA | hB | cA | cB (each 16.78MB fp16) = 67.2MB total
    const size_t state = (size_t)BB * HH * WW * FF;
    _Float16* blob = (_Float16*)d_ws;
    _Float16* hA = (_Float16*)((char*)d_ws + 32768);
    _Float16* hB = hA + state;
    _Float16* cA = hB + state;
    _Float16* cB = cA + state;

    build_frags<<<1, 64, 0, stream>>>(wk, wr, blob);

    dim3 pgrid(NPT, NPT, BB), block(64);
    // pair (0,1): no h/c input; writes h(1)->hA, c(1)->cA
    lstm_pair<1><<<pgrid, block, 0, stream>>>(x, 0, blob, bias,
                                              nullptr, hA, nullptr, cA);
    // pair (2,3): reads hA/cA; writes h(3)->hB, c(3)->cB
    lstm_pair<0><<<pgrid, block, 0, stream>>>(x, 2, blob, bias,
                                              hA, hB, cA, cB);
    // step 4 + epilogue
    dim3 lgrid(HH / TIW, WW / TIW, BB);
    lstm_last<<<lgrid, block, 0, stream>>>(x, blob, bias, hB, cB,
                                           gamma, beta, mean, var, dw, db, out);
}